// Round 5
// baseline (482.794 us; speedup 1.0000x reference)
//
#include <hip/hip_runtime.h>
#include <hip/hip_bf16.h>

typedef __bf16 bf16;
typedef __attribute__((ext_vector_type(8))) __bf16 bf16x8;
typedef __attribute__((ext_vector_type(4))) float f32x4;

static_assert(sizeof(bf16x8) == 16, "bf16x8 must be 16B");

constexpr int N_NODES = 10000;
constexpr int N_EDGES = 320000;
constexpr int KPAD    = 264;   // LDS row stride (bf16): 528B/row -> 2-way bank aliasing (free per m136)

// fast silu: v_exp + v_rcp (~1 ulp each; absmax margin is 0.575, we run at ~0.13)
__device__ __forceinline__ float silu_f(float x) {
  return x * __builtin_amdgcn_rcpf(1.0f + __expf(-x));
}

// pack two f32 -> (bf16(lo), bf16(hi)) in one u32; round-half-up via +0x8000 (<=1 ulp vs RNE)
__device__ __forceinline__ unsigned pk_bf16(float lo, float hi) {
  unsigned a = __float_as_uint(lo) + 0x8000u;
  unsigned b = __float_as_uint(hi) + 0x8000u;
  return __builtin_amdgcn_perm(b, a, 0x07060302u);
}

// ---- transposed-output MFMA, 32-ch out-slice (2 m-tiles) x 64 edges (4 n-tiles), K=256.
// WT pre-offset to this wave's 32-row slice. D row(q*4+rg)=ch, D col(lane&15)=edge.
__device__ __forceinline__ void mfmaT2_k256(const bf16* __restrict__ WT, int wstride,
                                            const bf16* Albs, int r, int q, f32x4 acc[2][4]) {
  for (int k0 = 0; k0 < 256; k0 += 32) {
    bf16x8 a[2], b[4];
#pragma unroll
    for (int mi = 0; mi < 2; ++mi)
      a[mi] = *(const bf16x8*)(WT + (size_t)(16 * mi + r) * wstride + k0 + q * 8);
#pragma unroll
    for (int ni = 0; ni < 4; ++ni)
      b[ni] = *(const bf16x8*)(Albs + (16 * ni + r) * KPAD + k0 + q * 8);
#pragma unroll
    for (int mi = 0; mi < 2; ++mi)
#pragma unroll
      for (int ni = 0; ni < 4; ++ni)
        acc[mi][ni] = __builtin_amdgcn_mfma_f32_16x16x32_bf16(a[mi], b[ni], acc[mi][ni], 0, 0, 0);
  }
}

// ---- prep (+fused hist)
__global__ __launch_bounds__(256) void prep_kernel(
    const float* __restrict__ h, const float* __restrict__ We1, const float* __restrict__ We2,
    const float* __restrict__ Wn1, const float* __restrict__ Wn2, const float* __restrict__ Wc1,
    const int* __restrict__ eidx,
    bf16* __restrict__ Hb, bf16* __restrict__ We1T, bf16* __restrict__ Wn1T,
    bf16* __restrict__ We2T, bf16* __restrict__ Wn2T, bf16* __restrict__ Wc1T,
    int* __restrict__ hist) {
  int bid = blockIdx.x, tid = threadIdx.x;
  if (bid < 10000) { int i = bid * 256 + tid; Hb[i] = (bf16)h[i]; return; }
  if (bid >= 11792) {
    int e = (bid - 11792) * 256 + tid;
    if (e < N_EDGES) atomicAdd(&hist[eidx[e]], 1);
    return;
  }
  int t = (bid - 10000) * 256 + tid;
  if (t < 131072) { int k = t >> 8, j = t & 255; We1T[j * 512 + k] = (bf16)We1[k * 256 + j]; return; }
  t -= 131072;
  if (t < 131072) { int k = t >> 8, j = t & 255; Wn1T[j * 512 + k] = (bf16)Wn1[k * 256 + j]; return; }
  t -= 131072;
  if (t < 65536) { int k = t >> 8, j = t & 255; We2T[j * 256 + k] = (bf16)We2[k * 256 + j]; return; }
  t -= 65536;
  if (t < 65536) { int k = t >> 8, j = t & 255; Wn2T[j * 256 + k] = (bf16)Wn2[k * 256 + j]; return; }
  t -= 65536;
  if (t < 65536) { int k = t >> 8, j = t & 255; Wc1T[j * 256 + k] = (bf16)Wc1[k * 256 + j]; return; }
}

__global__ __launch_bounds__(256) void scan_kernel(const int* __restrict__ hist,
                                                   int* __restrict__ base, int* __restrict__ cursor) {
  __shared__ int partial[256];
  int t = threadIdx.x;
  int s = 0;
  for (int i = 0; i < 40; ++i) { int idx = t * 40 + i; if (idx < N_NODES) s += hist[idx]; }
  partial[t] = s;
  __syncthreads();
  for (int d = 1; d < 256; d <<= 1) {
    int v = (t >= d) ? partial[t - d] : 0;
    __syncthreads();
    partial[t] += v;
    __syncthreads();
  }
  int run = partial[t] - s;  // exclusive
  for (int i = 0; i < 40; ++i) {
    int idx = t * 40 + i;
    if (idx < N_NODES) { base[idx] = run; cursor[idx] = run; run += hist[idx]; }
  }
}

__global__ __launch_bounds__(256) void scatter_kernel(const int* __restrict__ eidx, int* __restrict__ cursor,
                                                      int* __restrict__ rs, int* __restrict__ cs) {
  int e = blockIdx.x * 256 + threadIdx.x;
  if (e < N_EDGES) {
    int r = eidx[e], c = eidx[N_EDGES + e];
    int p = atomicAdd(&cursor[r], 1);
    rs[p] = r; cs[p] = c;
  }
}

// ---- P/Q GEMM (transposed-output). P gets be1 folded in.
__global__ __launch_bounds__(256, 2) void gemm_pq(const bf16* __restrict__ Hb,
                                                  const bf16* __restrict__ We1T,
                                                  const float* __restrict__ be1,
                                                  bf16* __restrict__ P, bf16* __restrict__ Q) {
  int tid = threadIdx.x, w = tid >> 6, lane = tid & 63, r = lane & 15, q = lane >> 4;
  int m0 = blockIdx.x * 64;
  int koff = blockIdx.y ? 256 : 0;
  bf16* OUT = blockIdx.y ? Q : P;
  bool addb = (blockIdx.y == 0);
  f32x4 acc[4][4];
#pragma unroll
  for (int mi = 0; mi < 4; ++mi)
#pragma unroll
    for (int ni = 0; ni < 4; ++ni) acc[mi][ni] = (f32x4){0.f, 0.f, 0.f, 0.f};

  for (int k0 = 0; k0 < 256; k0 += 32) {
    bf16x8 a[4], b[4];
#pragma unroll
    for (int mi = 0; mi < 4; ++mi)
      a[mi] = *(const bf16x8*)(We1T + (size_t)(w * 64 + 16 * mi + r) * 512 + koff + k0 + q * 8);
#pragma unroll
    for (int ni = 0; ni < 4; ++ni) {
      int m = m0 + 16 * ni + r; if (m > N_NODES - 1) m = N_NODES - 1;
      b[ni] = *(const bf16x8*)(Hb + (size_t)m * 256 + k0 + q * 8);
    }
#pragma unroll
    for (int mi = 0; mi < 4; ++mi)
#pragma unroll
      for (int ni = 0; ni < 4; ++ni)
        acc[mi][ni] = __builtin_amdgcn_mfma_f32_16x16x32_bf16(a[mi], b[ni], acc[mi][ni], 0, 0, 0);
  }
#pragma unroll
  for (int mi = 0; mi < 4; ++mi) {
    int ch = w * 64 + 16 * mi + 4 * q;
    float4 bv = addb ? *(const float4*)(be1 + ch) : (float4){0.f, 0.f, 0.f, 0.f};
#pragma unroll
    for (int ni = 0; ni < 4; ++ni) {
      int m = m0 + 16 * ni + r;
      if (m < N_NODES) {
        uint2 o;
        o.x = pk_bf16(acc[mi][ni][0] + bv.x, acc[mi][ni][1] + bv.y);
        o.y = pk_bf16(acc[mi][ni][2] + bv.z, acc[mi][ni][3] + bv.w);
        *(uint2*)(OUT + (size_t)m * 256 + ch) = o;
      }
    }
  }
}

// ---- edge kernel: 64 sorted edges/block, 512 threads (8 waves x 32-ch slices)
__global__ __launch_bounds__(512, 6) void edge_kernel(
    const float* __restrict__ coord, const int* __restrict__ rs, const int* __restrict__ cs,
    const float* __restrict__ We1,
    const float* __restrict__ be2, const float* __restrict__ bc1,
    const float* __restrict__ Wc2, const float* __restrict__ bc2,
    const bf16* __restrict__ P, const bf16* __restrict__ Q,
    const bf16* __restrict__ We2T, const bf16* __restrict__ Wc1T,
    float* __restrict__ agg_h, float* __restrict__ agg_c) {
  __shared__ __align__(16) bf16 buf[64 * KPAD];
  __shared__ int s_row[64], s_col[64];
  __shared__ float s_rad[64], s_cd[64][3], s_scal[64];
  __shared__ int s_rs[65];
  __shared__ int s_nrun;

  int tid = threadIdx.x;             // 0..511
  int e0 = blockIdx.x * 64;
  int w = tid >> 6, lane = tid & 63, r = lane & 15, q = lane >> 4;

  if (tid < 64) {
    int e = e0 + tid;
    int ri = rs[e], ci = cs[e];
    s_row[tid] = ri; s_col[tid] = ci;
    float dx = coord[3 * ri + 0] - coord[3 * ci + 0];
    float dy = coord[3 * ri + 1] - coord[3 * ci + 1];
    float dz = coord[3 * ri + 2] - coord[3 * ci + 2];
    s_cd[tid][0] = dx; s_cd[tid][1] = dy; s_cd[tid][2] = dz;
    s_rad[tid] = dx * dx + dy * dy + dz * dz;
    s_scal[tid] = 0.f;
  }
  __syncthreads();  // A

  // wave 0: run boundaries of sorted rows
  if (tid < 64) {
    bool bnd = (tid == 0) || (s_row[tid] != s_row[tid - 1]);
    unsigned long long m = __ballot(bnd);
    int rank = __popcll(m & ((1ull << tid) - 1ull));
    if (bnd) s_rs[rank] = tid;
    if (tid == 0) { int R = __popcll(m); s_nrun = R; s_rs[R] = 64; }
  }

  // e1 = silu(P[row] + Q[col] + radial*We1[512]) -> buf (be1 folded into P). 4 edges/thread.
  {
    int off = (tid & 31) * 8;
    int esub = tid >> 5;             // 0..15
    float4 wa = *(const float4*)(We1 + 512 * 256 + off);
    float4 wb = *(const float4*)(We1 + 512 * 256 + off + 4);
#pragma unroll
    for (int p = 0; p < 4; ++p) {
      int e = p * 16 + esub;
      int ri = s_row[e], ci = s_col[e];
      bf16x8 pv = *(const bf16x8*)(P + (size_t)ri * 256 + off);
      bf16x8 qv = *(const bf16x8*)(Q + (size_t)ci * 256 + off);
      float rad = s_rad[e];
      float f0 = silu_f((float)pv[0] + (float)qv[0] + rad * wa.x);
      float f1 = silu_f((float)pv[1] + (float)qv[1] + rad * wa.y);
      float f2 = silu_f((float)pv[2] + (float)qv[2] + rad * wa.z);
      float f3 = silu_f((float)pv[3] + (float)qv[3] + rad * wa.w);
      float f4 = silu_f((float)pv[4] + (float)qv[4] + rad * wb.x);
      float f5 = silu_f((float)pv[5] + (float)qv[5] + rad * wb.y);
      float f6 = silu_f((float)pv[6] + (float)qv[6] + rad * wb.z);
      float f7 = silu_f((float)pv[7] + (float)qv[7] + rad * wb.w);
      uint4 o;
      o.x = pk_bf16(f0, f1); o.y = pk_bf16(f2, f3);
      o.z = pk_bf16(f4, f5); o.w = pk_bf16(f6, f7);
      *(uint4*)(buf + e * KPAD + off) = o;
    }
  }
  __syncthreads();  // B

  // GEMM1: edge_feat = silu(e1 @ We2 + be2), 32-ch slice per wave
  {
    f32x4 acc[2][4];
#pragma unroll
    for (int mi = 0; mi < 2; ++mi)
#pragma unroll
      for (int ni = 0; ni < 4; ++ni) acc[mi][ni] = (f32x4){0.f, 0.f, 0.f, 0.f};
    mfmaT2_k256(We2T + (size_t)(w * 32) * 256, 256, buf, r, q, acc);
    __syncthreads();  // C: all reads of e1 done before overwrite
#pragma unroll
    for (int mi = 0; mi < 2; ++mi) {
      int ch = w * 32 + 16 * mi + 4 * q;
      float4 bv = *(const float4*)(be2 + ch);
#pragma unroll
      for (int ni = 0; ni < 4; ++ni) {
        int edge = 16 * ni + r;
        float f0 = silu_f(acc[mi][ni][0] + bv.x);
        float f1 = silu_f(acc[mi][ni][1] + bv.y);
        float f2 = silu_f(acc[mi][ni][2] + bv.z);
        float f3 = silu_f(acc[mi][ni][3] + bv.w);
        uint2 o; o.x = pk_bf16(f0, f1); o.y = pk_bf16(f2, f3);
        *(uint2*)(buf + edge * KPAD + ch) = o;
      }
    }
  }
  __syncthreads();  // D

  // GEMM2 k-loop (reads edge_feat from buf; nothing overwrites buf afterwards)
  f32x4 acc2[2][4];
#pragma unroll
  for (int mi = 0; mi < 2; ++mi)
#pragma unroll
    for (int ni = 0; ni < 4; ++ni) acc2[mi][ni] = (f32x4){0.f, 0.f, 0.f, 0.f};
  mfmaT2_k256(Wc1T + (size_t)(w * 32) * 256, 256, buf, r, q, acc2);

  // run-based agg_h column sums (also reads edge_feat); 512 threads -> 2 threads/col, odd/even runs
  {
    int col = tid & 255, start = tid >> 8;
    int R = s_nrun;
    for (int rr = start; rr < R; rr += 2) {
      int st = s_rs[rr], en = s_rs[rr + 1];
      float s = 0.f;
      for (int e = st; e < en; ++e) s += (float)buf[e * KPAD + col];
      atomicAdd(&agg_h[(size_t)s_row[st] * 256 + col], s);
    }
  }

  // c1 = silu(acc2 + bc1) stays in registers; dot with Wc2 slice; reduce into s_scal via LDS atomics
  {
    float part[4] = {0.f, 0.f, 0.f, 0.f};
#pragma unroll
    for (int mi = 0; mi < 2; ++mi) {
      int ch = w * 32 + 16 * mi + 4 * q;
      float4 bv = *(const float4*)(bc1 + ch);
      float4 wv = *(const float4*)(Wc2 + ch);
#pragma unroll
      for (int ni = 0; ni < 4; ++ni) {
        float f0 = silu_f(acc2[mi][ni][0] + bv.x);
        float f1 = silu_f(acc2[mi][ni][1] + bv.y);
        float f2 = silu_f(acc2[mi][ni][2] + bv.z);
        float f3 = silu_f(acc2[mi][ni][3] + bv.w);
        part[ni] += f0 * wv.x + f1 * wv.y + f2 * wv.z + f3 * wv.w;
      }
    }
#pragma unroll
    for (int ni = 0; ni < 4; ++ni)
      atomicAdd(&s_scal[16 * ni + r], part[ni]);
  }
  __syncthreads();  // E

  // coord aggregation: run-based, one lane per xyz component
  if (tid < 3) {
    int R = s_nrun;
    for (int rr = 0; rr < R; ++rr) {
      int st = s_rs[rr], en = s_rs[rr + 1];
      float s = 0.f;
      for (int e = st; e < en; ++e) s += s_cd[e][tid] * (s_scal[e] + bc2[0]);
      atomicAdd(&agg_c[3 * s_row[st] + tid], s);
    }
  }
}

// ---- node kernel (fused post): 512 threads, 8 waves x 32-ch slices
__global__ __launch_bounds__(512, 6) void node_kernel(
    const bf16* __restrict__ Hb, const float* __restrict__ agg_h,
    const int* __restrict__ hist, const float* __restrict__ coord, const float* __restrict__ agg_c,
    const bf16* __restrict__ Wn1T, const bf16* __restrict__ Wn2T,
    const float* __restrict__ bn1, const float* __restrict__ bn2,
    float* __restrict__ h_out, float* __restrict__ coord_out) {
  __shared__ __align__(16) bf16 buf[64 * KPAD];
  int tid = threadIdx.x, w = tid >> 6, lane = tid & 63, r = lane & 15, q = lane >> 4;
  int m0 = blockIdx.x * 64;

  if (tid < 64) {
    int m = m0 + tid;
    if (m < N_NODES) {
      float c = (float)hist[m]; if (c < 1.f) c = 1.f;
      float inv = __builtin_amdgcn_rcpf(c);
      coord_out[3 * m + 0] = coord[3 * m + 0] + agg_c[3 * m + 0] * inv;
      coord_out[3 * m + 1] = coord[3 * m + 1] + agg_c[3 * m + 1] * inv;
      coord_out[3 * m + 2] = coord[3 * m + 2] + agg_c[3 * m + 2] * inv;
    }
  }

  // layer1: 32-ch slice per wave, 64 nodes
  f32x4 acc[2][4];
#pragma unroll
  for (int mi = 0; mi < 2; ++mi)
#pragma unroll
    for (int ni = 0; ni < 4; ++ni) acc[mi][ni] = (f32x4){0.f, 0.f, 0.f, 0.f};
  const bf16* BT1 = Wn1T + (size_t)(w * 32) * 512;
  for (int k0 = 0; k0 < 256; k0 += 32) {
    bf16x8 a[2], b[4];
#pragma unroll
    for (int mi = 0; mi < 2; ++mi)
      a[mi] = *(const bf16x8*)(BT1 + (size_t)(16 * mi + r) * 512 + k0 + q * 8);
#pragma unroll
    for (int ni = 0; ni < 4; ++ni) {
      int m = m0 + 16 * ni + r; if (m > N_NODES - 1) m = N_NODES - 1;
      b[ni] = *(const bf16x8*)(Hb + (size_t)m * 256 + k0 + q * 8);
    }
#pragma unroll
    for (int mi = 0; mi < 2; ++mi)
#pragma unroll
      for (int ni = 0; ni < 4; ++ni)
        acc[mi][ni] = __builtin_amdgcn_mfma_f32_16x16x32_bf16(a[mi], b[ni], acc[mi][ni], 0, 0, 0);
  }
  for (int k0 = 0; k0 < 256; k0 += 32) {
    bf16x8 a[2], b[4];
#pragma unroll
    for (int mi = 0; mi < 2; ++mi)
      a[mi] = *(const bf16x8*)(BT1 + (size_t)(16 * mi + r) * 512 + 256 + k0 + q * 8);
#pragma unroll
    for (int ni = 0; ni < 4; ++ni) {
      int m = m0 + 16 * ni + r; if (m > N_NODES - 1) m = N_NODES - 1;
      const float* ap = agg_h + (size_t)m * 256 + k0 + q * 8;
      float4 u = *(const float4*)ap;
      float4 v = *(const float4*)(ap + 4);
      uint4 o;
      o.x = pk_bf16(u.x, u.y); o.y = pk_bf16(u.z, u.w);
      o.z = pk_bf16(v.x, v.y); o.w = pk_bf16(v.z, v.w);
      b[ni] = *(const bf16x8*)&o;
    }
#pragma unroll
    for (int mi = 0; mi < 2; ++mi)
#pragma unroll
      for (int ni = 0; ni < 4; ++ni)
        acc[mi][ni] = __builtin_amdgcn_mfma_f32_16x16x32_bf16(a[mi], b[ni], acc[mi][ni], 0, 0, 0);
  }
  __syncthreads();
  // epilogue -> buf[node][hidden]
#pragma unroll
  for (int mi = 0; mi < 2; ++mi) {
    int ch = w * 32 + 16 * mi + 4 * q;
    float4 bv = *(const float4*)(bn1 + ch);
#pragma unroll
    for (int ni = 0; ni < 4; ++ni) {
      int lm = 16 * ni + r;
      float f0 = silu_f(acc[mi][ni][0] + bv.x);
      float f1 = silu_f(acc[mi][ni][1] + bv.y);
      float f2 = silu_f(acc[mi][ni][2] + bv.z);
      float f3 = silu_f(acc[mi][ni][3] + bv.w);
      uint2 o; o.x = pk_bf16(f0, f1); o.y = pk_bf16(f2, f3);
      *(uint2*)(buf + lm * KPAD + ch) = o;
    }
  }
  __syncthreads();
  // layer2 -> h_out
  f32x4 acc2[2][4];
#pragma unroll
  for (int mi = 0; mi < 2; ++mi)
#pragma unroll
    for (int ni = 0; ni < 4; ++ni) acc2[mi][ni] = (f32x4){0.f, 0.f, 0.f, 0.f};
  mfmaT2_k256(Wn2T + (size_t)(w * 32) * 256, 256, buf, r, q, acc2);
#pragma unroll
  for (int mi = 0; mi < 2; ++mi) {
    int ch = w * 32 + 16 * mi + 4 * q;
    float4 bv = *(const float4*)(bn2 + ch);
#pragma unroll
    for (int ni = 0; ni < 4; ++ni) {
      int m = m0 + 16 * ni + r;
      if (m < N_NODES) {
        float4 o;
        o.x = acc2[mi][ni][0] + bv.x;
        o.y = acc2[mi][ni][1] + bv.y;
        o.z = acc2[mi][ni][2] + bv.z;
        o.w = acc2[mi][ni][3] + bv.w;
        *(float4*)(h_out + (size_t)m * 256 + ch) = o;
      }
    }
  }
}

extern "C" void kernel_launch(void* const* d_in, const int* in_sizes, int n_in,
                              void* d_out, int out_size, void* d_ws, size_t ws_size,
                              hipStream_t stream) {
  const float* h     = (const float*)d_in[0];
  const float* coord = (const float*)d_in[1];
  const int*   eidx  = (const int*)d_in[2];
  const float* We1 = (const float*)d_in[3];
  const float* be1 = (const float*)d_in[4];
  const float* We2 = (const float*)d_in[5];
  const float* be2 = (const float*)d_in[6];
  const float* Wn1 = (const float*)d_in[7];
  const float* bn1 = (const float*)d_in[8];
  const float* Wn2 = (const float*)d_in[9];
  const float* bn2 = (const float*)d_in[10];
  const float* Wc1 = (const float*)d_in[11];
  const float* bc1 = (const float*)d_in[12];
  const float* Wc2 = (const float*)d_in[13];
  const float* bc2 = (const float*)d_in[14];

  char* ws = (char*)d_ws;
  float* agg_h = (float*)(ws + 0);          // 10,240,000
  float* agg_c = (float*)(ws + 10240000);   //    120,000
  int*   hist  = (int*)  (ws + 10360000);   //     40,000
  int*   base  = (int*)  (ws + 10400000);   //     40,000
  int*   cursor= (int*)  (ws + 10440000);   //     40,000
  int*   rs    = (int*)  (ws + 10480000);   //  1,280,000
  int*   cs    = (int*)  (ws + 11760000);   //  1,280,000
  bf16* Hb   = (bf16*)(ws + 13040000);      //  5,120,000
  bf16* P    = (bf16*)(ws + 18160000);      //  5,120,000
  bf16* Q    = (bf16*)(ws + 23280000);      //  5,120,000
  bf16* We1T = (bf16*)(ws + 28400000);      //    262,144
  bf16* Wn1T = (bf16*)(ws + 28662144);      //    262,144
  bf16* We2T = (bf16*)(ws + 28924288);      //    131,072
  bf16* Wn2T = (bf16*)(ws + 29055360);      //    131,072
  bf16* Wc1T = (bf16*)(ws + 29186432);      //    131,072

  float* h_out = (float*)d_out;
  float* coord_out = h_out + (size_t)N_NODES * 256;

  hipMemsetAsync(ws, 0, 10400000, stream);  // agg_h + agg_c + hist
  prep_kernel<<<13042, 256, 0, stream>>>(h, We1, We2, Wn1, Wn2, Wc1, eidx,
                                         Hb, We1T, Wn1T, We2T, Wn2T, Wc1T, hist);
  scan_kernel<<<1, 256, 0, stream>>>(hist, base, cursor);
  scatter_kernel<<<1250, 256, 0, stream>>>(eidx, cursor, rs, cs);
  gemm_pq<<<dim3(157, 2), 256, 0, stream>>>(Hb, We1T, be1, P, Q);
  edge_kernel<<<5000, 512, 0, stream>>>(coord, rs, cs, We1, be2, bc1, Wc2, bc2,
                                        P, Q, We2T, Wc1T, agg_h, agg_c);
  node_kernel<<<157, 512, 0, stream>>>(Hb, agg_h, hist, coord, agg_c,
                                       Wn1T, Wn2T, bn1, bn2, h_out, coord_out);
}